// Round 1
// 201.392 us; speedup vs baseline: 6.2079x; 6.2079x over previous
//
#include <hip/hip_runtime.h>
#include <hip/hip_fp16.h>
#include <math.h>

// FrFT (Ozaktas, 0.5<a<1.5): x[256,4096] f32, order f32 -> Re(complex64) f32
// out[b*4096+j]. R14: move both GEMM stages onto MFMA f16.
//
//   stage1 (sinc interp):  xiT[b,s] = sum_i x[b,i] * w1(s-i)       (K=4096)
//   stage2 (chirp GEMM):   out[b,j] = scale * sum_r u[r,b] * cos(ph(j,r))
//     split into even-r (u=x) and odd-r (u=xiT) segments; k-permutation is
//     legal because MFMA A/B share the same lane->k map.
//
// Layout assumptions (CDNA4 16x16x32): A row = lane&15, B col = lane&15,
// k-slots symmetric across A/B (so only consistency matters); C/D col=lane&15,
// row=(lane>>4)*4+reg (m89-verified). Zero LDS, zero barriers; split-K=8 via
// device-scope f32 atomic add. Stage-1 f32 partials stage through `out`
// (ws only guarantees 2 MB), convert kernel writes fp16 xiT + re-zeros out.
// Weight formulas identical to the R13-proven scalar kernel (numerics parity).

#define NN 4096
#define BB 256
#define KK (2*NN - 1)

typedef unsigned int uint;
typedef __attribute__((ext_vector_type(4))) float f32x4;
typedef __attribute__((ext_vector_type(8))) _Float16 half8;
typedef __attribute__((ext_vector_type(4))) _Float16 half4;

struct LitConsts { float c, q, scale, pe; };

__device__ __forceinline__ LitConsts get_lit(const float* order) {
  float a = order[0];
  float alpha = a * (float)M_PI * 0.5f;
  float sina = sinf(alpha);
  float tana2 = tanf(alpha * 0.5f);
  LitConsts L;
  L.c = (float)M_PI / (float)NN / sina / 4.0f;
  L.q = ((float)M_PI / (float)NN) * (tana2 * 0.25f);
  L.scale = sqrtf(L.c / (float)M_PI);
  L.pe = -(1.0f - a) * (float)M_PI * 0.25f;
  return L;
}

__device__ __forceinline__ void atomAddF(float* p, float v) {
  __hip_atomic_fetch_add(p, v, __ATOMIC_RELAXED, __HIP_MEMORY_SCOPE_AGENT);
}

__device__ __forceinline__ float xload(const float* __restrict__ x, uint idx, uint cap) {
  return (idx < cap) ? x[idx] : 0.f;
}

// ---- zero f32 buffer (in float4 quads) ----
__global__ __launch_bounds__(256) void k_zero(float* __restrict__ p, uint n4) {
  uint q = blockIdx.x * 256u + threadIdx.x;
  if (q < n4) {
    f32x4 z = {0.f, 0.f, 0.f, 0.f};
    ((f32x4*)p)[q] = z;
  }
}

// ---- stage 1: MFMA sinc-interp, f32 partials atomically into outacc[b*NN+s] ----
// grid (16, 4, 8): x = s-block (256 wide, 4 waves x 64), y = b-block (64), z = i-chunk (512)
__global__ __launch_bounds__(256) void s1_mfma(const float* __restrict__ x,
                                               float* __restrict__ outacc,
                                               uint out_capf) {
  const int lane = threadIdx.x & 63, wave = threadIdx.x >> 6;
  const int s_blk = blockIdx.x * 256 + wave * 64;
  const int b0 = blockIdx.y * 64;
  const int l15 = lane & 15, lhi = lane >> 4;
  const int i_base = blockIdx.z * 512;

  f32x4 acc[4][4] = {};  // [fm(b)][fs(s)]

  for (int st = 0; st < 16; ++st) {
    const int i0 = i_base + st * 32 + lhi * 8;  // this lane's k-base
    // A fragments from x (f32 -> f16)
    half8 a[4];
#pragma unroll
    for (int fm = 0; fm < 4; ++fm) {
      const float* px = x + (size_t)(b0 + fm * 16 + l15) * NN + i0;
      f32x4 u0 = *(const f32x4*)px;
      f32x4 u1 = *(const f32x4*)(px + 4);
      half8 h;
#pragma unroll
      for (int e = 0; e < 4; ++e) { h[e] = (_Float16)u0[e]; h[e + 4] = (_Float16)u1[e]; }
      a[fm] = h;
    }
    // B fragments: Toeplitz sinc weights w1(t), t = s - i  (same formula as R13)
#pragma unroll
    for (int fs = 0; fs < 4; ++fs) {
      const int sl = s_blk + fs * 16 + l15;
      half8 bh;
#pragma unroll
      for (int e = 0; e < 8; ++e) {
        const int t = sl - (i0 + e);
        const float sgn = (t & 1) ? -0.63661977236758134f : 0.63661977236758134f;
        bh[e] = (_Float16)__fdividef(sgn, (float)(2 * t + 1));
      }
#pragma unroll
      for (int fm = 0; fm < 4; ++fm)
        acc[fm][fs] = __builtin_amdgcn_mfma_f32_16x16x32_f16(a[fm], bh, acc[fm][fs], 0, 0, 0);
    }
  }
  // atomic accumulate partials (f32) into outacc[b*NN + s]
#pragma unroll
  for (int fm = 0; fm < 4; ++fm) {
    const int brow = b0 + fm * 16 + lhi * 4;
#pragma unroll
    for (int fs = 0; fs < 4; ++fs) {
      const int sl = s_blk + fs * 16 + l15;
#pragma unroll
      for (int rr = 0; rr < 4; ++rr) {
        uint idx = (uint)(brow + rr) * NN + (uint)sl;
        if (idx < out_capf) atomAddF(&outacc[idx], acc[fm][fs][rr]);
      }
    }
  }
}

// ---- stage 1.5: xiT = fp16(outacc); outacc = 0 (ready for stage 2 atomics) ----
__global__ __launch_bounds__(256) void s1_cvt(float* __restrict__ accbuf,
                                              _Float16* __restrict__ xiT, uint n4) {
  uint q = blockIdx.x * 256u + threadIdx.x;
  if (q < n4) {
    f32x4 v = ((f32x4*)accbuf)[q];
    half4 h;
#pragma unroll
    for (int e = 0; e < 4; ++e) h[e] = (_Float16)v[e];
    ((half4*)xiT)[q] = h;
    f32x4 z = {0.f, 0.f, 0.f, 0.f};
    ((f32x4*)accbuf)[q] = z;
  }
}

// ---- stage 2: chirp GEMM via MFMA; ODD=0 -> even r from x, ODD=1 -> odd r from xiT ----
// grid (16, 4, 4): x = j-block (256 wide, 4 waves x 64), y = b-block (64), z = i-chunk (1024)
template <int ODD>
__global__ __launch_bounds__(256) void s2_mfma(const float* __restrict__ x,
                                               const _Float16* __restrict__ xiT,
                                               const float* __restrict__ order,
                                               float* __restrict__ out,
                                               uint out_capf) {
  const int lane = threadIdx.x & 63, wave = threadIdx.x >> 6;
  const int j_blk = blockIdx.x * 256 + wave * 64;
  const int b0 = blockIdx.y * 64;
  const int l15 = lane & 15, lhi = lane >> 4;
  const int c_base = blockIdx.z * 1024;
  const LitConsts L = get_lit(order);

  // per-lane j-dependent phase base per fragment column
  float jbase[4];
#pragma unroll
  for (int fj = 0; fj < 4; ++fj) {
    const int jl = j_blk + fj * 16 + l15;
    const int n = 2 * jl - (NN - 1);
    jbase[fj] = fmaf(-L.q, (float)(n * n), L.pe);
  }

  f32x4 acc[4][4] = {};  // [fm(b)][fj(j)]

  for (int st = 0; st < 32; ++st) {
    const int i0 = c_base + st * 32 + lhi * 8;
    // A fragments
    half8 a[4];
    if (ODD) {
#pragma unroll
      for (int fm = 0; fm < 4; ++fm)
        a[fm] = *(const half8*)(xiT + (size_t)(b0 + fm * 16 + l15) * NN + i0);
    } else {
#pragma unroll
      for (int fm = 0; fm < 4; ++fm) {
        const float* px = x + (size_t)(b0 + fm * 16 + l15) * NN + i0;
        f32x4 u0 = *(const f32x4*)px;
        f32x4 u1 = *(const f32x4*)(px + 4);
        half8 h;
#pragma unroll
        for (int e = 0; e < 4; ++e) { h[e] = (_Float16)u0[e]; h[e + 4] = (_Float16)u1[e]; }
        a[fm] = h;
      }
    }
    // B fragments: folded-phase chirp weights (identical math to R13)
#pragma unroll
    for (int fj = 0; fj < 4; ++fj) {
      const int jl = j_blk + fj * 16 + l15;
      half8 bh;
#pragma unroll
      for (int e = 0; e < 8; ++e) {
        const int i = i0 + e;
        const int r = 2 * i + ODD;
        const int d = 2 * jl - r;
        const int k = r - (NN - 1);
        float ph = fmaf(L.c, (float)(d * d), fmaf(-L.q, (float)(k * k), jbase[fj]));
        float w = __cosf(ph);
        if (ODD && i > NN - 2) w = 0.f;  // pad element r=8191 does not exist
        bh[e] = (_Float16)w;
      }
#pragma unroll
      for (int fm = 0; fm < 4; ++fm)
        acc[fm][fj] = __builtin_amdgcn_mfma_f32_16x16x32_f16(a[fm], bh, acc[fm][fj], 0, 0, 0);
    }
  }
  // epilogue: out[b*NN + j] += scale * partial
#pragma unroll
  for (int fm = 0; fm < 4; ++fm) {
    const int brow = b0 + fm * 16 + lhi * 4;
#pragma unroll
    for (int fj = 0; fj < 4; ++fj) {
      const int jl = j_blk + fj * 16 + l15;
#pragma unroll
      for (int rr = 0; rr < 4; ++rr) {
        uint idx = (uint)(brow + rr) * NN + (uint)jl;
        if (idx < out_capf) atomAddF(&out[idx], L.scale * acc[fm][fj][rr]);
      }
    }
  }
}

// ======================= R13 proven fallback (small ws) =======================

__global__ __launch_bounds__(256) void frft_interp(const float* __restrict__ x,
                                                   __half* __restrict__ xi,
                                                   int b_lo, int cnt,
                                                   uint xi_cap, uint x_cap) {
  __shared__ __align__(16) float wt1[32][64];
  __shared__ __align__(16) float xt[32][64];
  const int tid = threadIdx.x;
  const int s0 = blockIdx.x * 64, cb0 = blockIdx.y * 64;
  const int tx = tid & 15, ty = tid >> 4;
  const int ss0 = ty * 4, bb0 = tx * 4;

  float acc[4][4] = {};
  for (int i0 = 0; i0 < NN; i0 += 32) {
#pragma unroll
    for (int e = 0; e < 8; ++e) {
      int idx = tid + e * 256, qq = idx >> 6, ss = idx & 63;
      int t = s0 + ss - (i0 + qq);
      float sgn = (t & 1) ? -0.63661977236758134f : 0.63661977236758134f;
      wt1[qq][ss] = __fdividef(sgn, (float)(2 * t + 1));
    }
#pragma unroll
    for (int e = 0; e < 8; ++e) {
      int idx = tid + e * 256, qq = idx >> 6, bb = idx & 63;
      xt[qq][bb] = xload(x, (uint)(b_lo + cb0 + bb) * NN + (i0 + qq), x_cap);
    }
    __syncthreads();
#pragma unroll
    for (int qq = 0; qq < 32; ++qq) {
      float4 wv = *(const float4*)&wt1[qq][ss0];
      float4 uv = *(const float4*)&xt[qq][bb0];
      float w[4] = {wv.x, wv.y, wv.z, wv.w};
      float u[4] = {uv.x, uv.y, uv.z, uv.w};
#pragma unroll
      for (int aa = 0; aa < 4; ++aa)
#pragma unroll
        for (int cc = 0; cc < 4; ++cc) acc[aa][cc] = fmaf(w[aa], u[cc], acc[aa][cc]);
    }
    __syncthreads();
  }
#pragma unroll
  for (int aa = 0; aa < 4; ++aa) {
    int s = s0 + ss0 + aa;
    if (s < NN - 1) {
#pragma unroll
      for (int cc = 0; cc < 4; ++cc) {
        int cb = cb0 + bb0 + cc;
        if (cb < cnt) {
          uint o = (uint)s * (uint)cnt + (uint)cb;
          if (o < xi_cap) xi[o] = __float2half(acc[aa][cc]);
        }
      }
    }
  }
}

#define TJ 32
#define TB 64
#define TK 32
__global__ __launch_bounds__(256) void frft_gemm(const float* __restrict__ x,
                                                 const __half* __restrict__ xi,
                                                 const float* __restrict__ order,
                                                 float* __restrict__ out,
                                                 int b_lo, int cnt,
                                                 uint xi_cap, uint x_cap,
                                                 uint out_capf) {
  __shared__ __align__(16) float wt[TK][TJ];
  __shared__ __align__(16) float ut[TK][TB];
  const int tid = threadIdx.x;
  const int j0 = blockIdx.x * TJ, cb0 = blockIdx.y * TB;
  const int tx = tid & 15, ty = tid >> 4;
  const int jj0 = ty * 2, bb0 = tx * 4;

  LitConsts L = get_lit(order);
  float acc[2][4] = {};

  for (int r0 = 0; r0 < KK; r0 += TK) {
#pragma unroll
    for (int e = 0; e < 4; ++e) {
      int idx = tid + e * 256, qq = idx >> 5, jj = idx & 31;
      int r = r0 + qq;
      float wv = 0.f;
      if (r < KK) {
        int j = j0 + jj;
        int n = 2 * j - (NN - 1);
        int d = 2 * j - r;
        int k = r - (NN - 1);
        float base = fmaf(-L.q, (float)(n * n), L.pe);
        float ph = fmaf(L.c, (float)(d * d), fmaf(-L.q, (float)(k * k), base));
        wv = __cosf(ph);
      }
      wt[qq][jj] = wv;
    }
#pragma unroll
    for (int e = 0; e < 8; ++e) {
      int idx = tid + e * 256, qq = idx >> 6, bb = idx & 63;
      int r = r0 + qq, cb = cb0 + bb;
      float v = 0.f;
      if (r < KK && cb < cnt) {
        if (r & 1) {
          uint o = (uint)(r >> 1) * (uint)cnt + (uint)cb;
          v = (o < xi_cap) ? __half2float(xi[o]) : 0.f;
        } else {
          v = xload(x, (uint)(b_lo + cb) * NN + (uint)(r >> 1), x_cap);
        }
      }
      ut[qq][bb] = v;
    }
    __syncthreads();
#pragma unroll
    for (int qq = 0; qq < TK; ++qq) {
      float2 wv = *(const float2*)&wt[qq][jj0];
      float4 uv = *(const float4*)&ut[qq][bb0];
      float w[2] = {wv.x, wv.y};
      float u[4] = {uv.x, uv.y, uv.z, uv.w};
#pragma unroll
      for (int aa = 0; aa < 2; ++aa)
#pragma unroll
        for (int cc = 0; cc < 4; ++cc)
          acc[aa][cc] = fmaf(w[aa], u[cc], acc[aa][cc]);
    }
    __syncthreads();
  }

#pragma unroll
  for (int aa = 0; aa < 2; ++aa) {
    int j = j0 + jj0 + aa;
#pragma unroll
    for (int cc = 0; cc < 4; ++cc) {
      int cb = cb0 + bb0 + cc;
      if (cb < cnt) {
        uint idx = (uint)(b_lo + cb) * NN + (uint)j;
        if (idx < out_capf) out[idx] = L.scale * acc[aa][cc];
      }
    }
  }
}

__global__ __launch_bounds__(256) void frft_gemm1(const float* __restrict__ x,
                                                  const float* __restrict__ order,
                                                  float* __restrict__ out,
                                                  uint x_cap, uint out_capf) {
  __shared__ float xrow[NN];
  __shared__ float xio[NN - 1];
  __shared__ float red[4][64];
  const int tid = threadIdx.x;
  const int j0 = blockIdx.x * 64;
  LitConsts L = get_lit(order);

#pragma unroll
  for (int e = 0; e < 16; ++e) {
    int i = tid + e * 256;
    xrow[i] = xload(x, (uint)255 * NN + (uint)i, x_cap);
  }
  __syncthreads();
#pragma unroll
  for (int m = 0; m < 16; ++m) {
    int s = tid + m * 256;
    if (s < NN - 1) {
      float a0 = 0.f;
      for (int i = 0; i < NN; ++i) {
        int t = s - i;
        float sgn = (t & 1) ? -0.63661977236758134f : 0.63661977236758134f;
        a0 = fmaf(xrow[i], __fdividef(sgn, (float)(2 * t + 1)), a0);
      }
      xio[s] = a0;
    }
  }
  __syncthreads();

  const int ty = tid >> 6, jj = tid & 63;
  const int j = j0 + jj;
  const int n = 2 * j - (NN - 1);
  const float base = fmaf(-L.q, (float)(n * n), L.pe);
  float acc = 0.f;
  int rend = (ty + 1) * 2048; if (rend > KK) rend = KK;
  for (int r = ty * 2048; r < rend; ++r) {
    int d = 2 * j - r;
    int k = r - (NN - 1);
    float ph = fmaf(L.c, (float)(d * d), fmaf(-L.q, (float)(k * k), base));
    float u = (r & 1) ? xio[r >> 1] : xrow[r >> 1];
    acc = fmaf(__cosf(ph), u, acc);
  }
  red[ty][jj] = acc;
  __syncthreads();
  if (ty == 0) {
    float t = red[0][jj] + red[1][jj] + red[2][jj] + red[3][jj];
    uint idx = (uint)255 * NN + (uint)j;
    if (idx < out_capf) out[idx] = L.scale * t;
  }
}

extern "C" void kernel_launch(void* const* d_in, const int* in_sizes, int n_in,
                              void* d_out, int out_size, void* d_ws, size_t ws_size,
                              hipStream_t stream) {
  const float* x     = (const float*)d_in[0];
  const float* order = (const float*)d_in[1];
  float* outf = (float*)d_out;
  const uint x_cap    = (uint)in_sizes[0];
  const uint out_capf = (uint)out_size;
  const size_t ws_halves = ws_size / 2;

  // ---- R14 MFMA path: needs 2 MB ws for xiT[b][4096] fp16, exact shapes ----
  if (ws_size >= (size_t)NN * BB * 2 &&
      out_capf >= (uint)NN * BB && x_cap >= (uint)NN * BB) {
    _Float16* xiT = (_Float16*)d_ws;
    const uint n4 = (uint)((size_t)NN * BB / 4);  // 262144 float4 quads
    k_zero<<<dim3((n4 + 255) / 256), 256, 0, stream>>>(outf, n4);
    s1_mfma<<<dim3(16, 4, 8), 256, 0, stream>>>(x, outf, out_capf);
    s1_cvt<<<dim3((n4 + 255) / 256), 256, 0, stream>>>(outf, xiT, n4);
    s2_mfma<0><<<dim3(16, 4, 4), 256, 0, stream>>>(x, xiT, order, outf, out_capf);
    s2_mfma<1><<<dim3(16, 4, 4), 256, 0, stream>>>(x, xiT, order, outf, out_capf);
    return;
  }

  // ---- R13 proven fallback paths ----
  if (ws_halves >= (size_t)(NN - 1) * BB) {
    uint xi_cap = (uint)((size_t)(NN - 1) * BB);
    frft_interp<<<dim3(64, 4), 256, 0, stream>>>(x, (__half*)d_ws, 0, BB, xi_cap, x_cap);
    frft_gemm<<<dim3(NN / TJ, BB / TB), 256, 0, stream>>>(x, (__half*)d_ws, order, outf,
                                                          0, BB, xi_cap, x_cap, out_capf);
  } else {
    struct Chunk { int lo, cnt; };
    const Chunk ch[6] = { {0,170}, {170,57}, {227,19}, {246,6}, {252,2}, {254,1} };
    for (int i = 0; i < 6; ++i) {
      const Chunk& c = ch[i];
      uint off = (uint)(c.lo + c.cnt) * (uint)NN;
      __half* xp = (__half*)(outf + off);
      size_t need = (size_t)(NN - 1) * (size_t)c.cnt;
      size_t avail = (out_capf > off) ? (size_t)(out_capf - off) * 2 : 0;
      uint xi_cap = (uint)(need < avail ? need : avail);
      frft_interp<<<dim3(64, (unsigned)((c.cnt + 63) / 64)), 256, 0, stream>>>(
          x, xp, c.lo, c.cnt, xi_cap, x_cap);
      frft_gemm<<<dim3(NN / TJ, (unsigned)((c.cnt + TB - 1) / TB)), 256, 0, stream>>>(
          x, xp, order, outf, c.lo, c.cnt, xi_cap, x_cap, out_capf);
    }
    if (ws_halves >= (size_t)(NN - 1)) {
      uint xi_cap = (uint)(NN - 1);
      frft_interp<<<dim3(64, 1), 256, 0, stream>>>(x, (__half*)d_ws, 255, 1, xi_cap, x_cap);
      frft_gemm<<<dim3(NN / TJ, 1), 256, 0, stream>>>(x, (__half*)d_ws, order, outf,
                                                      255, 1, xi_cap, x_cap, out_capf);
    } else {
      frft_gemm1<<<64, 256, 0, stream>>>(x, order, outf, x_cap, out_capf);
    }
  }
}